// Round 3
// baseline (66.341 us; speedup 1.0000x reference)
//
#include <hip/hip_runtime.h>

#define WL 512   // window_len (t and o dims)
#define NV 64    // n_var
#define LR 16    // low rank
#define NB 512   // batch

__device__ __forceinline__ float tanh_fast(float x) {
    // tanh(x) = 1 - 2/(exp(2x)+1); exact at +-inf saturation, ~1e-7 abs err
    float e = __expf(2.0f * x);
    return 1.0f - 2.0f / (e + 1.0f);
}

// K1: tmp[b,k,v] = sum_t tanh(g[v]*x[b,t,v]) * A[t,k]
// grid = 512 (one block per b), block = 512 threads (8 waves)
// thread: v = tid&63, t-group tg = tid>>6 owns t = tg*64 .. tg*64+63
// A rows are read via wave-uniform addresses (readfirstlane-forced) so the
// compiler scalarizes them to s_load and feeds FMAs from SGPRs.
__global__ __launch_bounds__(512, 4) void k_tmp(
    const float* __restrict__ x, const float* __restrict__ gating,
    const float* __restrict__ A, float* __restrict__ tmp)
{
    __shared__ float red[8 * LR * NV];  // 32 KiB (reduction buffer only)
    const int tid = threadIdx.x;
    const int b = blockIdx.x;

    const int v = tid & 63;
    const int tg = __builtin_amdgcn_readfirstlane(tid >> 6);
    const float g = gating[v];

    float acc[LR];
#pragma unroll
    for (int k = 0; k < LR; ++k) acc[k] = 0.f;

    const float* xb = x + (size_t)b * (WL * NV) + (size_t)tg * 64 * NV + v;
    const float* Abase = A + (size_t)tg * 64 * LR;

#pragma unroll 4
    for (int i = 0; i < 64; ++i) {
        const float x1 = tanh_fast(g * xb[i * NV]);      // 256B/wave, coalesced
        const float* Ar = Abase + i * LR;                // wave-uniform -> s_load
#pragma unroll
        for (int k = 0; k < LR; ++k) acc[k] = fmaf(x1, Ar[k], acc[k]);
    }

    // reduce the 8 t-group partials via LDS (one-time, cheap)
#pragma unroll
    for (int k = 0; k < LR; ++k) red[(tg * LR + k) * NV + v] = acc[k];
    __syncthreads();
#pragma unroll
    for (int p = tid; p < LR * NV; p += 512) {   // 1024 (k,v) pairs, 2/thread
        float s = 0.f;
#pragma unroll
        for (int t = 0; t < 8; ++t) s += red[t * (LR * NV) + p];
        tmp[(size_t)b * (LR * NV) + p] = s;
    }
}

// K2: out[b,o,v] = x[b,o,v] + bias[o,v] + sum_k tmp[b,k,v]*B[k,o,v]
// grid = (64 b-chunks of 8) x (32 o-tiles of 16), block = 256 (4 waves)
// (byte-identical to the verified 48.8 us version)
__global__ __launch_bounds__(256, 4) void k_out(
    const float* __restrict__ x, const float* __restrict__ bias,
    const float* __restrict__ Bm, const float* __restrict__ tmp,
    float* __restrict__ out)
{
    const int tid = threadIdx.x;
    const int v = tid & 63;
    const int og = tid >> 6;
    const int o_base = blockIdx.y * 16 + og * 4;
    const int b0 = blockIdx.x * 8;

    float Breg[4][LR];
#pragma unroll
    for (int j = 0; j < 4; ++j) {
        const int o = o_base + j;
#pragma unroll
        for (int k = 0; k < LR; ++k)
            Breg[j][k] = Bm[((size_t)k * WL + o) * NV + v];  // 256B/wave, coalesced
    }
    float breg[4];
#pragma unroll
    for (int j = 0; j < 4; ++j) breg[j] = bias[(o_base + j) * NV + v];

    for (int bi = 0; bi < 8; ++bi) {
        const int b = b0 + bi;
        const float* tb = tmp + (size_t)b * (LR * NV) + v;
        float tr[LR];
#pragma unroll
        for (int k = 0; k < LR; ++k) tr[k] = tb[k * NV];     // L1/L2-resident
        const float* xb = x + (size_t)b * WL * NV;
        float* ob = out + (size_t)b * WL * NV;
#pragma unroll
        for (int j = 0; j < 4; ++j) {
            const int o = o_base + j;
            float acc = breg[j];
#pragma unroll
            for (int k = 0; k < LR; ++k) acc += tr[k] * Breg[j][k];
            ob[o * NV + v] = xb[o * NV + v] + acc;
        }
    }
}

extern "C" void kernel_launch(void* const* d_in, const int* in_sizes, int n_in,
                              void* d_out, int out_size, void* d_ws, size_t ws_size,
                              hipStream_t stream) {
    const float* x      = (const float*)d_in[0];  // [512,512,64,1]
    const float* gating = (const float*)d_in[1];  // [64]
    const float* bias   = (const float*)d_in[2];  // [512,64]
    const float* A      = (const float*)d_in[3];  // [512,16]
    const float* Bm     = (const float*)d_in[4];  // [16,512,64]
    float* out = (float*)d_out;
    float* tmp = (float*)d_ws;                    // 512*16*64 f32 = 2 MiB scratch

    // ATTRIBUTION PROBE (this round only): k_tmp launched twice.
    // Idempotent — second launch rewrites tmp with identical values before
    // k_out consumes it. dur_us_new - 48.8us = K1's standalone duration,
    // which the rocprof top-5 (saturated by 39us harness fills) cannot show.
    k_tmp<<<NB, 512, 0, stream>>>(x, gating, A, tmp);
    k_tmp<<<NB, 512, 0, stream>>>(x, gating, A, tmp);
    k_out<<<dim3(64, 32), 256, 0, stream>>>(x, bias, Bm, tmp, out);
}

// Round 4
// 50.448 us; speedup vs baseline: 1.3150x; 1.3150x over previous
//
#include <hip/hip_runtime.h>

#define WL 512   // window_len (t and o dims)
#define NV 64    // n_var
#define LR 16    // low rank
#define NB 512   // batch

__device__ __forceinline__ float tanh_fast(float x) {
    // tanh(x) = 1 - 2/(exp(2x)+1); exact at +-inf saturation, ~1e-7 abs err
    float e = __expf(2.0f * x);
    return 1.0f - 2.0f / (e + 1.0f);
}

// K1: tmp[b,v,k] = sum_t tanh(g[v]*x[b,t,v]) * A[t,k]   (NOTE: [b,v,k] layout!)
// grid = 512 (one block per b), block = 512 threads (8 waves)
// thread: v = tid&63, t-group tg = tid>>6 owns t = tg*64 .. tg*64+63
// A rows read via wave-uniform (readfirstlane-forced) addresses -> s_load/SGPR,
// zero LDS traffic in the hot loop. Epilogue writes tmp TRANSPOSED ([b,v,k])
// so K2 can read each v-row as 4x float4. red[] padded to 17 floats/row to
// keep both the partial-write and the transposed re-read bank-conflict-free.
__global__ __launch_bounds__(512, 4) void k_tmp(
    const float* __restrict__ x, const float* __restrict__ gating,
    const float* __restrict__ A, float* __restrict__ tmp)
{
    __shared__ float red[8 * NV * 17];  // [tg][v][k+pad] = 34.8 KiB
    const int tid = threadIdx.x;
    const int b = blockIdx.x;

    const int v = tid & 63;
    const int tg = __builtin_amdgcn_readfirstlane(tid >> 6);
    const float g = gating[v];

    float acc[LR];
#pragma unroll
    for (int k = 0; k < LR; ++k) acc[k] = 0.f;

    const float* xb = x + (size_t)b * (WL * NV) + (size_t)tg * 64 * NV + v;
    const float* Abase = A + (size_t)tg * 64 * LR;

#pragma unroll 4
    for (int i = 0; i < 64; ++i) {
        const float x1 = tanh_fast(g * xb[i * NV]);      // 256B/wave, coalesced
        const float* Ar = Abase + i * LR;                // wave-uniform -> s_load
#pragma unroll
        for (int k = 0; k < LR; ++k) acc[k] = fmaf(x1, Ar[k], acc[k]);
    }

    // partial write: lanes v, stride 17 dwords -> banks (17v+k)%32, 2 lanes/bank (free)
    float* rrow = &red[(tg * NV + v) * 17];
#pragma unroll
    for (int k = 0; k < LR; ++k) rrow[k] = acc[k];
    __syncthreads();

    // reduce 8 partials; p = v2*16 + k2 -> tmp[b][v2][k2], fully coalesced store
#pragma unroll
    for (int p = tid; p < LR * NV; p += 512) {   // 2 iterations
        const int v2 = p >> 4;
        const int k2 = p & 15;
        float s = 0.f;
#pragma unroll
        for (int t = 0; t < 8; ++t) s += red[(t * NV + v2) * 17 + k2];
        tmp[(size_t)b * (LR * NV) + p] = s;
    }
}

// K2: out[b,o,v] = x[b,o,v] + bias[o,v] + sum_k tmp[b,v,k]*B[k,o,v]
// grid = (32 b-chunks of 16) x (32 o-tiles of 16), block = 256 (4 waves)
//   -> 1024 blocks = exactly 4/CU at launch_bounds(256,4) = 16 waves/CU
// thread: v = tid&63, wave og = tid>>6 owns o = oTile*16 + og*4 + j, j=0..3
// B slice in registers (64 VGPR), reused across 16 batches (B L2 traffic halved).
// tmp row [v][0..15] is contiguous -> 4x float4 per batch (was 16 dwords).
// x prefetched one batch ahead (the only long-latency chain).
__global__ __launch_bounds__(256, 4) void k_out(
    const float* __restrict__ x, const float* __restrict__ bias,
    const float* __restrict__ Bm, const float* __restrict__ tmp,
    float* __restrict__ out)
{
    const int tid = threadIdx.x;
    const int v = tid & 63;
    const int og = tid >> 6;
    const int o_base = blockIdx.y * 16 + og * 4;
    const int b0 = blockIdx.x * 16;

    float Breg[4][LR];
#pragma unroll
    for (int j = 0; j < 4; ++j) {
        const int o = o_base + j;
#pragma unroll
        for (int k = 0; k < LR; ++k)
            Breg[j][k] = Bm[((size_t)k * WL + o) * NV + v];  // 256B/wave, coalesced
    }
    float breg[4];
#pragma unroll
    for (int j = 0; j < 4; ++j) breg[j] = bias[(o_base + j) * NV + v];

    // prefetch x for batch b0
    float xr[4], xrn[4];
    {
        const float* xb = x + (size_t)b0 * WL * NV;
#pragma unroll
        for (int j = 0; j < 4; ++j) xr[j] = xb[(o_base + j) * NV + v];
    }

    for (int bi = 0; bi < 16; ++bi) {
        const int b = b0 + bi;

        // prefetch next batch's x early (HBM/L3 latency hides under FMAs)
        if (bi < 15) {
            const float* xbn = x + (size_t)(b + 1) * WL * NV;
#pragma unroll
            for (int j = 0; j < 4; ++j) xrn[j] = xbn[(o_base + j) * NV + v];
        }

        // tmp row for this lane's v: 16 contiguous floats = 4x float4
        const float4* tb4 = (const float4*)(tmp + (size_t)b * (LR * NV) + v * LR);
        float tr[LR];
        {
            float4 t4;
            t4 = tb4[0]; tr[0]=t4.x; tr[1]=t4.y; tr[2]=t4.z; tr[3]=t4.w;
            t4 = tb4[1]; tr[4]=t4.x; tr[5]=t4.y; tr[6]=t4.z; tr[7]=t4.w;
            t4 = tb4[2]; tr[8]=t4.x; tr[9]=t4.y; tr[10]=t4.z; tr[11]=t4.w;
            t4 = tb4[3]; tr[12]=t4.x; tr[13]=t4.y; tr[14]=t4.z; tr[15]=t4.w;
        }

        float* ob = out + (size_t)b * WL * NV;
#pragma unroll
        for (int j = 0; j < 4; ++j) {
            float acc = breg[j];
#pragma unroll
            for (int k = 0; k < LR; ++k) acc += tr[k] * Breg[j][k];
            ob[(o_base + j) * NV + v] = xr[j] + acc;
        }

        if (bi < 15) {
#pragma unroll
            for (int j = 0; j < 4; ++j) xr[j] = xrn[j];
        }
    }
}

extern "C" void kernel_launch(void* const* d_in, const int* in_sizes, int n_in,
                              void* d_out, int out_size, void* d_ws, size_t ws_size,
                              hipStream_t stream) {
    const float* x      = (const float*)d_in[0];  // [512,512,64,1]
    const float* gating = (const float*)d_in[1];  // [64]
    const float* bias   = (const float*)d_in[2];  // [512,64]
    const float* A      = (const float*)d_in[3];  // [512,16]
    const float* Bm     = (const float*)d_in[4];  // [16,512,64]
    float* out = (float*)d_out;
    float* tmp = (float*)d_ws;                    // 512*16*64 f32 = 2 MiB scratch ([b,v,k])

    k_tmp<<<NB, 512, 0, stream>>>(x, gating, A, tmp);
    k_out<<<dim3(32, 32), 256, 0, stream>>>(x, bias, Bm, tmp, out);
}